// Round 2
// baseline (2540.098 us; speedup 1.0000x reference)
//
#include <hip/hip_runtime.h>
#include <hip/hip_bf16.h>

// Fused linear + cross-entropy forward.
//   x: [BT, H] fp32, weight: [V, H] fp32, target: [BT] int (harness int32)
//   out: [0] = loss (fp32), [1..BT] = lse (fp32)
//
// K1: bf16 MFMA GEMM over 128x128 logit tiles + per-tile (max, sumexp) partials
// K2: per-row reduce of partials -> lse, nll
// K3: mean -> loss

typedef __bf16 bf16x8 __attribute__((ext_vector_type(8)));
typedef float f32x16 __attribute__((ext_vector_type(16)));

#define BM 128
#define BN 128
#define BK 32
#define LDK 40  // padded LDS row stride in bf16 elems (80B: uniform bank spread)

__device__ __forceinline__ unsigned pkbf(float a, float b) {
  __hip_bfloat162 h = __float22bfloat162_rn(float2{a, b});
  unsigned r;
  __builtin_memcpy(&r, &h, 4);  // bit_cast rejected: __hip_bfloat162 not trivially copyable
  return r;
}

__global__ __launch_bounds__(256, 2)
void k_gemm_lse(const float* __restrict__ x, const float* __restrict__ w,
                const int* __restrict__ tgt,
                float* __restrict__ ws_m, float* __restrict__ ws_s,
                float* __restrict__ ws_t,
                int H, int NCB, int ROWB)
{
  __shared__ unsigned short As[2][BM * LDK];
  __shared__ unsigned short Bs[2][BN * LDK];

  const int bid  = blockIdx.x;
  const int rowb = bid % ROWB;   // row-block fastest: consecutive blocks share weight strip (L3)
  const int cb   = bid / ROWB;
  const int row0 = rowb * BM;
  const int col0 = cb * BN;

  const int t    = threadIdx.x;
  const int lane = t & 63;
  const int wv   = t >> 6;       // wave 0..3, each owns 32 rows x 128 cols

  // staging: thread covers LDS row sr, 16 consecutive k at offset sk
  const int sr = t >> 1;         // 0..127
  const int sk = (t & 1) * 16;   // 0 or 16

  const float* xa = x + (size_t)(row0 + sr) * H + sk;
  const float* wb = w + (size_t)(col0 + sr) * H + sk;

  float4 ra[4], rb[4];
  #pragma unroll
  for (int i = 0; i < 4; ++i) {
    ra[i] = *(const float4*)(xa + i * 4);
    rb[i] = *(const float4*)(wb + i * 4);
  }

  auto stage = [&](int buf) {
    uint4 p0, p1;
    p0.x = pkbf(ra[0].x, ra[0].y); p0.y = pkbf(ra[0].z, ra[0].w);
    p0.z = pkbf(ra[1].x, ra[1].y); p0.w = pkbf(ra[1].z, ra[1].w);
    p1.x = pkbf(ra[2].x, ra[2].y); p1.y = pkbf(ra[2].z, ra[2].w);
    p1.z = pkbf(ra[3].x, ra[3].y); p1.w = pkbf(ra[3].z, ra[3].w);
    *(uint4*)&As[buf][sr * LDK + sk]     = p0;
    *(uint4*)&As[buf][sr * LDK + sk + 8] = p1;
    p0.x = pkbf(rb[0].x, rb[0].y); p0.y = pkbf(rb[0].z, rb[0].w);
    p0.z = pkbf(rb[1].x, rb[1].y); p0.w = pkbf(rb[1].z, rb[1].w);
    p1.x = pkbf(rb[2].x, rb[2].y); p1.y = pkbf(rb[2].z, rb[2].w);
    p1.z = pkbf(rb[3].x, rb[3].y); p1.w = pkbf(rb[3].z, rb[3].w);
    *(uint4*)&Bs[buf][sr * LDK + sk]     = p0;
    *(uint4*)&Bs[buf][sr * LDK + sk + 8] = p1;
  };

  stage(0);
  __syncthreads();

  f32x16 acc[4] = {};

  const int rlo = lane & 31;
  const int hi  = lane >> 5;
  const int NT  = H / BK;
  int cur = 0;

  for (int kt = 0; kt < NT; ++kt) {
    const bool pf = (kt + 1 < NT);
    if (pf) {  // issue next-tile global loads early; conversion below waits vmcnt
      xa += BK; wb += BK;
      #pragma unroll
      for (int i = 0; i < 4; ++i) {
        ra[i] = *(const float4*)(xa + i * 4);
        rb[i] = *(const float4*)(wb + i * 4);
      }
    }
    const unsigned short* A = As[cur];
    const unsigned short* B = Bs[cur];
    #pragma unroll
    for (int ks = 0; ks < 2; ++ks) {
      const int koff = ks * 16 + hi * 8;
      bf16x8 a = *(const bf16x8*)&A[(wv * 32 + rlo) * LDK + koff];
      #pragma unroll
      for (int nf = 0; nf < 4; ++nf) {
        bf16x8 b = *(const bf16x8*)&B[(nf * 32 + rlo) * LDK + koff];
        acc[nf] = __builtin_amdgcn_mfma_f32_32x32x16_bf16(a, b, acc[nf], 0, 0, 0);
      }
    }
    if (pf) stage(cur ^ 1);
    __syncthreads();
    cur ^= 1;
  }

  // Epilogue: per-row (over this block's 128 cols) max and sum-exp.
  // C/D layout (verified): col = lane&31, row = (reg&3) + 8*(reg>>2) + 4*(lane>>5)
  #pragma unroll
  for (int reg = 0; reg < 16; ++reg) {
    const int row = wv * 32 + (reg & 3) + 8 * (reg >> 2) + 4 * hi;
    float mx = fmaxf(fmaxf(acc[0][reg], acc[1][reg]), fmaxf(acc[2][reg], acc[3][reg]));
    #pragma unroll
    for (int m = 1; m < 32; m <<= 1) mx = fmaxf(mx, __shfl_xor(mx, m, 64));
    float s = 0.f;
    #pragma unroll
    for (int nf = 0; nf < 4; ++nf) s += expf(acc[nf][reg] - mx);
    #pragma unroll
    for (int m = 1; m < 32; m <<= 1) s += __shfl_xor(s, m, 64);
    const int grow = row0 + row;
    if (rlo == 0) {
      ws_m[(size_t)grow * NCB + cb] = mx;
      ws_s[(size_t)grow * NCB + cb] = s;
    }
    const int tv = tgt[grow];
    #pragma unroll
    for (int nf = 0; nf < 4; ++nf) {
      if (tv == col0 + nf * 32 + rlo) ws_t[grow] = acc[nf][reg];
    }
  }
}

__global__ void k_rowlse(const float* __restrict__ ws_m, const float* __restrict__ ws_s,
                         const float* __restrict__ ws_t, const int* __restrict__ tgt,
                         float* __restrict__ out, float* __restrict__ ws_nll, int NCB)
{
  const int row = blockIdx.x;
  const int t = threadIdx.x;
  const float* pm = ws_m + (size_t)row * NCB;
  const float* ps = ws_s + (size_t)row * NCB;
  __shared__ float red[8];

  float M = -3.0e38f;
  for (int j = t; j < NCB; j += 256) M = fmaxf(M, pm[j]);
  #pragma unroll
  for (int m = 1; m < 64; m <<= 1) M = fmaxf(M, __shfl_xor(M, m, 64));
  if ((t & 63) == 0) red[t >> 6] = M;
  __syncthreads();
  M = fmaxf(fmaxf(red[0], red[1]), fmaxf(red[2], red[3]));

  float S = 0.f;
  for (int j = t; j < NCB; j += 256) S += ps[j] * expf(pm[j] - M);
  #pragma unroll
  for (int m = 1; m < 64; m <<= 1) S += __shfl_xor(S, m, 64);
  if ((t & 63) == 0) red[4 + (t >> 6)] = S;
  __syncthreads();

  if (t == 0) {
    S = red[4] + red[5] + red[6] + red[7];
    const float lse = M + logf(S);
    out[1 + row] = lse;
    const int tv = tgt[row];
    ws_nll[row] = (tv != -100) ? (lse - ws_t[row]) : 0.f;
  }
}

__global__ void k_loss(const float* __restrict__ ws_nll, const int* __restrict__ tgt,
                       float* __restrict__ out, int BT)
{
  const int t = threadIdx.x;
  float s = 0.f, c = 0.f;
  for (int i = t; i < BT; i += 256) {
    s += ws_nll[i];
    c += (tgt[i] != -100) ? 1.f : 0.f;
  }
  __shared__ float rs[4], rc[4];
  #pragma unroll
  for (int m = 1; m < 64; m <<= 1) { s += __shfl_xor(s, m, 64); c += __shfl_xor(c, m, 64); }
  if ((t & 63) == 0) { rs[t >> 6] = s; rc[t >> 6] = c; }
  __syncthreads();
  if (t == 0) {
    s = rs[0] + rs[1] + rs[2] + rs[3];
    c = rc[0] + rc[1] + rc[2] + rc[3];
    out[0] = s / c;
  }
}

extern "C" void kernel_launch(void* const* d_in, const int* in_sizes, int n_in,
                              void* d_out, int out_size, void* d_ws, size_t ws_size,
                              hipStream_t stream)
{
  const float* x  = (const float*)d_in[0];
  const float* w  = (const float*)d_in[1];
  const int* tgt  = (const int*)d_in[2];
  float* out      = (float*)d_out;

  const int BT = in_sizes[2];
  const int H  = in_sizes[0] / BT;          // 2048
  const int V  = in_sizes[1] / H;           // 128000
  const int ROWB = BT / BM;                 // 16
  const int NCB  = V / BN;                  // 1000

  // workspace layout (floats): m[BT*NCB] | s[BT*NCB] | tgt_logit[BT] | nll[BT]  (~16.4 MB)
  float* ws_m   = (float*)d_ws;
  float* ws_s   = ws_m + (size_t)BT * NCB;
  float* ws_t   = ws_s + (size_t)BT * NCB;
  float* ws_nll = ws_t + BT;

  k_gemm_lse<<<ROWB * NCB, 256, 0, stream>>>(x, w, tgt, ws_m, ws_s, ws_t, H, NCB, ROWB);
  k_rowlse<<<BT, 256, 0, stream>>>(ws_m, ws_s, ws_t, tgt, out, ws_nll, NCB);
  k_loss<<<1, 256, 0, stream>>>(ws_nll, tgt, out, BT);
}

// Round 3
// 1563.921 us; speedup vs baseline: 1.6242x; 1.6242x over previous
//
#include <hip/hip_runtime.h>
#include <hip/hip_bf16.h>

// Fused linear + cross-entropy forward.
//   x: [BT, H] fp32, weight: [V, H] fp32, target: [BT] int32
//   out: [0] = loss (fp32), [1..BT] = lse (fp32)
//
// Fast path (needs ~549MB ws):
//   K0: fp32 -> bf16 pre-pass, tiled [tile][kc4][row128][8] = the LDS image
//   K1: bf16 MFMA GEMM, global_load_lds staging, conflict-free ds_reads
//   K2: per-row reduce of partials -> lse, nll;  K3: mean -> loss
// Fallback path (small ws): round-2 reg-staged kernel.

typedef __bf16 bf16x8 __attribute__((ext_vector_type(8)));
typedef float f32x16 __attribute__((ext_vector_type(16)));

#define BM 128
#define BN 128
#define BK 32
#define LDK 40      // fallback kernel LDS pad
#define TILE_E 4096 // elems per 128x32 bf16 tile

__device__ __forceinline__ unsigned pkbf(float a, float b) {
  __hip_bfloat162 h = __float22bfloat162_rn(float2{a, b});
  unsigned r;
  __builtin_memcpy(&r, &h, 4);
  return r;
}

// global -> LDS direct copy, 16B per lane. LDS dest must be wave-uniform base.
// addrspace casts via integer (generic LDS addr low 32 bits == LDS offset).
__device__ __forceinline__ void gl16(const void* g, const void* l) {
  using GP = const unsigned __attribute__((address_space(1)))*;
  using LP = unsigned __attribute__((address_space(3)))*;
  __builtin_amdgcn_global_load_lds((GP)(unsigned long long)g,
                                   (LP)(unsigned)(unsigned long long)l, 16, 0, 0);
}

// ---- K0: convert + retile. One block per 128x32 tile. ----
// dst tile = [kc(4)][row(128)][8], tiles linear as (rowtile * NT + kt).
__global__ __launch_bounds__(256)
void k_cvt_tile(const float* __restrict__ src, __bf16* __restrict__ dst, int H, int NT)
{
  const int bid = blockIdx.x;
  const int tv = bid / NT, kt = bid % NT;
  const int t = threadIdx.x;
  const int r = t >> 1, hh = (t & 1) * 16;
  const float* s = src + (size_t)(tv * 128 + r) * H + kt * 32 + hh;
  float4 f0 = ((const float4*)s)[0];
  float4 f1 = ((const float4*)s)[1];
  float4 f2 = ((const float4*)s)[2];
  float4 f3 = ((const float4*)s)[3];
  uint4 p0, p1;
  p0.x = pkbf(f0.x, f0.y); p0.y = pkbf(f0.z, f0.w);
  p0.z = pkbf(f1.x, f1.y); p0.w = pkbf(f1.z, f1.w);
  p1.x = pkbf(f2.x, f2.y); p1.y = pkbf(f2.z, f2.w);
  p1.z = pkbf(f3.x, f3.y); p1.w = pkbf(f3.z, f3.w);
  __bf16* d = dst + (size_t)bid * TILE_E + ((t & 1) * 2) * 1024 + r * 8;
  *(uint4*)d = p0;
  *(uint4*)(d + 1024) = p1;
}

// ---- K1 fast: bf16 GEMM + per-tile (max, sumexp) partials ----
__global__ __launch_bounds__(256, 3)
void k_gemm_lse_bf(const __bf16* __restrict__ xb, const __bf16* __restrict__ wb,
                   const int* __restrict__ tgt,
                   float* __restrict__ ws_m, float* __restrict__ ws_s,
                   float* __restrict__ ws_t,
                   int NT, int NCB, int ROWB)
{
  __shared__ __bf16 As[2][TILE_E];
  __shared__ __bf16 Bs[2][TILE_E];

  const int bid  = blockIdx.x;
  const int rowb = bid % ROWB;   // row-block fastest: weight strip L2/L3 reuse
  const int cb   = bid / ROWB;
  const int row0 = rowb * BM;
  const int col0 = cb * BN;

  const int t    = threadIdx.x;
  const int lane = t & 63;
  const int wv   = t >> 6;

  const __bf16* ga = xb + (size_t)(rowb * NT) * TILE_E;
  const __bf16* gb = wb + (size_t)(cb * NT) * TILE_E;

  auto stage = [&](int buf, int kt) {
    const __bf16* a = ga + (size_t)kt * TILE_E + wv * 512 + lane * 8;
    const __bf16* b = gb + (size_t)kt * TILE_E + wv * 512 + lane * 8;
    gl16(a,        &As[buf][wv * 512]);
    gl16(a + 2048, &As[buf][2048 + wv * 512]);
    gl16(b,        &Bs[buf][wv * 512]);
    gl16(b + 2048, &Bs[buf][2048 + wv * 512]);
  };

  stage(0, 0);
  __syncthreads();

  f32x16 acc[4] = {};
  const int rlo = lane & 31;
  const int hi  = lane >> 5;
  int cur = 0;

  for (int kt = 0; kt < NT; ++kt) {
    if (kt + 1 < NT) stage(cur ^ 1, kt + 1);
    const __bf16* A = As[cur];
    const __bf16* B = Bs[cur];
    #pragma unroll
    for (int ks = 0; ks < 2; ++ks) {
      const int kc = ks * 2 + hi;
      bf16x8 a = *(const bf16x8*)&A[kc * 1024 + (wv * 32 + rlo) * 8];
      #pragma unroll
      for (int nf = 0; nf < 4; ++nf) {
        bf16x8 b = *(const bf16x8*)&B[kc * 1024 + (nf * 32 + rlo) * 8];
        acc[nf] = __builtin_amdgcn_mfma_f32_32x32x16_bf16(a, b, acc[nf], 0, 0, 0);
      }
    }
    __syncthreads();
    cur ^= 1;
  }

  // Epilogue: per-row (over this block's 128 cols) max and sum-exp.
  // C/D layout: col = lane&31, row = (reg&3) + 8*(reg>>2) + 4*(lane>>5)
  #pragma unroll
  for (int reg = 0; reg < 16; ++reg) {
    const int row = wv * 32 + (reg & 3) + 8 * (reg >> 2) + 4 * hi;
    float mx = fmaxf(fmaxf(acc[0][reg], acc[1][reg]), fmaxf(acc[2][reg], acc[3][reg]));
    #pragma unroll
    for (int m = 1; m < 32; m <<= 1) mx = fmaxf(mx, __shfl_xor(mx, m, 64));
    float s = 0.f;
    #pragma unroll
    for (int nf = 0; nf < 4; ++nf) s += expf(acc[nf][reg] - mx);
    #pragma unroll
    for (int m = 1; m < 32; m <<= 1) s += __shfl_xor(s, m, 64);
    const int grow = row0 + row;
    if (rlo == 0) {
      ws_m[(size_t)grow * NCB + cb] = mx;
      ws_s[(size_t)grow * NCB + cb] = s;
    }
    const int tv = tgt[grow];
    #pragma unroll
    for (int nf = 0; nf < 4; ++nf) {
      if (tv == col0 + nf * 32 + rlo) ws_t[grow] = acc[nf][reg];
    }
  }
}

// ---- K1 fallback: round-2 reg-staged kernel (used if ws too small) ----
__global__ __launch_bounds__(256, 2)
void k_gemm_lse(const float* __restrict__ x, const float* __restrict__ w,
                const int* __restrict__ tgt,
                float* __restrict__ ws_m, float* __restrict__ ws_s,
                float* __restrict__ ws_t,
                int H, int NCB, int ROWB)
{
  __shared__ unsigned short As[2][BM * LDK];
  __shared__ unsigned short Bs[2][BN * LDK];

  const int bid  = blockIdx.x;
  const int rowb = bid % ROWB;
  const int cb   = bid / ROWB;
  const int row0 = rowb * BM;
  const int col0 = cb * BN;

  const int t    = threadIdx.x;
  const int lane = t & 63;
  const int wv   = t >> 6;
  const int sr = t >> 1;
  const int sk = (t & 1) * 16;

  const float* xa = x + (size_t)(row0 + sr) * H + sk;
  const float* wb = w + (size_t)(col0 + sr) * H + sk;

  float4 ra[4], rb[4];
  #pragma unroll
  for (int i = 0; i < 4; ++i) {
    ra[i] = *(const float4*)(xa + i * 4);
    rb[i] = *(const float4*)(wb + i * 4);
  }

  auto stage = [&](int buf) {
    uint4 p0, p1;
    p0.x = pkbf(ra[0].x, ra[0].y); p0.y = pkbf(ra[0].z, ra[0].w);
    p0.z = pkbf(ra[1].x, ra[1].y); p0.w = pkbf(ra[1].z, ra[1].w);
    p1.x = pkbf(ra[2].x, ra[2].y); p1.y = pkbf(ra[2].z, ra[2].w);
    p1.z = pkbf(ra[3].x, ra[3].y); p1.w = pkbf(ra[3].z, ra[3].w);
    *(uint4*)&As[buf][sr * LDK + sk]     = p0;
    *(uint4*)&As[buf][sr * LDK + sk + 8] = p1;
    p0.x = pkbf(rb[0].x, rb[0].y); p0.y = pkbf(rb[0].z, rb[0].w);
    p0.z = pkbf(rb[1].x, rb[1].y); p0.w = pkbf(rb[1].z, rb[1].w);
    p1.x = pkbf(rb[2].x, rb[2].y); p1.y = pkbf(rb[2].z, rb[2].w);
    p1.z = pkbf(rb[3].x, rb[3].y); p1.w = pkbf(rb[3].z, rb[3].w);
    *(uint4*)&Bs[buf][sr * LDK + sk]     = p0;
    *(uint4*)&Bs[buf][sr * LDK + sk + 8] = p1;
  };

  stage(0);
  __syncthreads();

  f32x16 acc[4] = {};
  const int rlo = lane & 31;
  const int hi  = lane >> 5;
  const int NT  = H / BK;
  int cur = 0;

  for (int kt = 0; kt < NT; ++kt) {
    const bool pf = (kt + 1 < NT);
    if (pf) {
      xa += BK; wb += BK;
      #pragma unroll
      for (int i = 0; i < 4; ++i) {
        ra[i] = *(const float4*)(xa + i * 4);
        rb[i] = *(const float4*)(wb + i * 4);
      }
    }
    const unsigned short* A = As[cur];
    const unsigned short* B = Bs[cur];
    #pragma unroll
    for (int ks = 0; ks < 2; ++ks) {
      const int koff = ks * 16 + hi * 8;
      bf16x8 a = *(const bf16x8*)&A[(wv * 32 + rlo) * LDK + koff];
      #pragma unroll
      for (int nf = 0; nf < 4; ++nf) {
        bf16x8 b = *(const bf16x8*)&B[(nf * 32 + rlo) * LDK + koff];
        acc[nf] = __builtin_amdgcn_mfma_f32_32x32x16_bf16(a, b, acc[nf], 0, 0, 0);
      }
    }
    if (pf) stage(cur ^ 1);
    __syncthreads();
    cur ^= 1;
  }

  #pragma unroll
  for (int reg = 0; reg < 16; ++reg) {
    const int row = wv * 32 + (reg & 3) + 8 * (reg >> 2) + 4 * hi;
    float mx = fmaxf(fmaxf(acc[0][reg], acc[1][reg]), fmaxf(acc[2][reg], acc[3][reg]));
    #pragma unroll
    for (int m = 1; m < 32; m <<= 1) mx = fmaxf(mx, __shfl_xor(mx, m, 64));
    float s = 0.f;
    #pragma unroll
    for (int nf = 0; nf < 4; ++nf) s += expf(acc[nf][reg] - mx);
    #pragma unroll
    for (int m = 1; m < 32; m <<= 1) s += __shfl_xor(s, m, 64);
    const int grow = row0 + row;
    if (rlo == 0) {
      ws_m[(size_t)grow * NCB + cb] = mx;
      ws_s[(size_t)grow * NCB + cb] = s;
    }
    const int tv = tgt[grow];
    #pragma unroll
    for (int nf = 0; nf < 4; ++nf) {
      if (tv == col0 + nf * 32 + rlo) ws_t[grow] = acc[nf][reg];
    }
  }
}

__global__ void k_rowlse(const float* __restrict__ ws_m, const float* __restrict__ ws_s,
                         const float* __restrict__ ws_t, const int* __restrict__ tgt,
                         float* __restrict__ out, float* __restrict__ ws_nll, int NCB)
{
  const int row = blockIdx.x;
  const int t = threadIdx.x;
  const float* pm = ws_m + (size_t)row * NCB;
  const float* ps = ws_s + (size_t)row * NCB;
  __shared__ float red[8];

  float M = -3.0e38f;
  for (int j = t; j < NCB; j += 256) M = fmaxf(M, pm[j]);
  #pragma unroll
  for (int m = 1; m < 64; m <<= 1) M = fmaxf(M, __shfl_xor(M, m, 64));
  if ((t & 63) == 0) red[t >> 6] = M;
  __syncthreads();
  M = fmaxf(fmaxf(red[0], red[1]), fmaxf(red[2], red[3]));

  float S = 0.f;
  for (int j = t; j < NCB; j += 256) S += ps[j] * expf(pm[j] - M);
  #pragma unroll
  for (int m = 1; m < 64; m <<= 1) S += __shfl_xor(S, m, 64);
  if ((t & 63) == 0) red[4 + (t >> 6)] = S;
  __syncthreads();   // (round-2 had a cross-wave race here)

  if (t == 0) {
    S = red[4] + red[5] + red[6] + red[7];
    const float lse = M + logf(S);
    out[1 + row] = lse;
    const int tv = tgt[row];
    ws_nll[row] = (tv != -100) ? (lse - ws_t[row]) : 0.f;
  }
}

__global__ void k_loss(const float* __restrict__ ws_nll, const int* __restrict__ tgt,
                       float* __restrict__ out, int BT)
{
  const int t = threadIdx.x;
  float s = 0.f, c = 0.f;
  for (int i = t; i < BT; i += 256) {
    s += ws_nll[i];
    c += (tgt[i] != -100) ? 1.f : 0.f;
  }
  __shared__ float rs[4], rc[4];
  #pragma unroll
  for (int m = 1; m < 64; m <<= 1) { s += __shfl_xor(s, m, 64); c += __shfl_xor(c, m, 64); }
  if ((t & 63) == 0) { rs[t >> 6] = s; rc[t >> 6] = c; }
  __syncthreads();
  if (t == 0) {
    s = rs[0] + rs[1] + rs[2] + rs[3];
    c = rc[0] + rc[1] + rc[2] + rc[3];
    out[0] = s / c;
  }
}

extern "C" void kernel_launch(void* const* d_in, const int* in_sizes, int n_in,
                              void* d_out, int out_size, void* d_ws, size_t ws_size,
                              hipStream_t stream)
{
  const float* x  = (const float*)d_in[0];
  const float* w  = (const float*)d_in[1];
  const int* tgt  = (const int*)d_in[2];
  float* out      = (float*)d_out;

  const int BT = in_sizes[2];
  const int H  = in_sizes[0] / BT;          // 2048
  const int V  = in_sizes[1] / H;           // 128000
  const int ROWB = BT / BM;                 // 16
  const int NCB  = V / BN;                  // 1000
  const int NT   = H / BK;                  // 64

  const size_t bf_elems   = (size_t)BT * H + (size_t)V * H;
  const size_t need_bytes = bf_elems * 2 + ((size_t)2 * BT * NCB + 2 * (size_t)BT) * 4;

  if (ws_size >= need_bytes) {
    // fast path: ws = x_bf | w_bf | m | s | tgt_logit | nll
    __bf16* x_bf = (__bf16*)d_ws;
    __bf16* w_bf = x_bf + (size_t)BT * H;
    float* ws_m   = (float*)(w_bf + (size_t)V * H);
    float* ws_s   = ws_m + (size_t)BT * NCB;
    float* ws_t   = ws_s + (size_t)BT * NCB;
    float* ws_nll = ws_t + BT;

    k_cvt_tile<<<(V / 128) * NT, 256, 0, stream>>>(w, w_bf, H, NT);
    k_cvt_tile<<<(BT / 128) * NT, 256, 0, stream>>>(x, x_bf, H, NT);
    k_gemm_lse_bf<<<ROWB * NCB, 256, 0, stream>>>(x_bf, w_bf, tgt, ws_m, ws_s, ws_t, NT, NCB, ROWB);
    k_rowlse<<<BT, 256, 0, stream>>>(ws_m, ws_s, ws_t, tgt, out, ws_nll, NCB);
    k_loss<<<1, 256, 0, stream>>>(ws_nll, tgt, out, BT);
  } else {
    // fallback: ws = m | s | tgt_logit | nll
    float* ws_m   = (float*)d_ws;
    float* ws_s   = ws_m + (size_t)BT * NCB;
    float* ws_t   = ws_s + (size_t)BT * NCB;
    float* ws_nll = ws_t + BT;

    k_gemm_lse<<<ROWB * NCB, 256, 0, stream>>>(x, w, tgt, ws_m, ws_s, ws_t, H, NCB, ROWB);
    k_rowlse<<<BT, 256, 0, stream>>>(ws_m, ws_s, ws_t, tgt, out, ws_nll, NCB);
    k_loss<<<1, 256, 0, stream>>>(ws_nll, tgt, out, BT);
  }
}